// Round 2
// baseline (914.886 us; speedup 1.0000x reference)
//
#include <hip/hip_runtime.h>
#include <hip/hip_bf16.h>
#include <cstdint>
#include <cstddef>

typedef __hip_bfloat16 bf16;
typedef __attribute__((ext_vector_type(8))) short short8;
typedef __attribute__((ext_vector_type(4))) float f32x4;

// async global->LDS, 16B per lane. LDS dest = wave-uniform base + lane*16.
__device__ __forceinline__ void gload_lds16(const void* g, void* l) {
    __builtin_amdgcn_global_load_lds((const __attribute__((address_space(1))) void*)g,
                                     (__attribute__((address_space(3))) void*)l,
                                     16, 0, 0);
}

// ------------- fp32 -> bf16 transpose: out[c][r] = bf16(in[r][c]) ------------
__global__ __launch_bounds__(256)
void transpose_cvt(const float* __restrict__ in, bf16* __restrict__ out, int R, int C)
{
    __shared__ float tile[32][33];
    const int tx = threadIdx.x & 31;
    const int ty = threadIdx.x >> 5;      // 0..7
    const int c0 = blockIdx.x * 32;
    const int r0 = blockIdx.y * 32;
    #pragma unroll
    for (int j = 0; j < 32; j += 8)
        tile[ty + j][tx] = in[(size_t)(r0 + ty + j) * C + c0 + tx];
    __syncthreads();
    #pragma unroll
    for (int j = 0; j < 32; j += 8)
        out[(size_t)(c0 + ty + j) * R + r0 + tx] = __float2bfloat16(tile[tx][ty + j]);
}

// ------------- tiny per-tag table gemms (64x768, fp32 all the way) -----------
__global__ __launch_bounds__(256)
void tag_gemm_a(const float* __restrict__ te, const float* __restrict__ Wv,
                const float* __restrict__ bv, float* __restrict__ t1)
{
    const int idx = blockIdx.x * 256 + threadIdx.x;   // 64*768 threads
    const int i = idx / 768, j = idx - i * 768;
    float acc = bv[j];
    const float* a = te + (size_t)i * 768;
    for (int k = 0; k < 768; ++k)
        acc += a[k] * Wv[(size_t)k * 768 + j];
    t1[idx] = acc;
}

__global__ __launch_bounds__(256)
void tag_gemm_b(const float* __restrict__ t1, const float* __restrict__ Wo,
                const float* __restrict__ bo, float* __restrict__ ptab)
{
    const int idx = blockIdx.x * 256 + threadIdx.x;
    const int i = idx / 768, j = idx - i * 768;
    float acc = bo[j];
    const float* a = t1 + (size_t)i * 768;
    for (int k = 0; k < 768; ++k)
        acc += a[k] * Wo[(size_t)k * 768 + j];
    ptab[idx] = acc;
}

// ------------- x = we + ptab[tag]*mask; xn = bf16(LN1(x)) --------------------
__global__ __launch_bounds__(256)
void addtag_ln(const float* __restrict__ we, const int* __restrict__ tags,
               const int* __restrict__ mask, const float* __restrict__ ptab,
               const float* __restrict__ g, const float* __restrict__ b,
               bf16* __restrict__ out)
{
    const int row = blockIdx.x;
    const int t = threadIdx.x;
    const int lane = t & 63, wid = t >> 6;
    const int tag = tags[row];
    const float msk = (float)mask[row];
    const float* wr = we + (size_t)row * 768;
    const float* pt = ptab + (size_t)tag * 768;
    float x[3];
    float s = 0.f, s2 = 0.f;
    #pragma unroll
    for (int j = 0; j < 3; ++j) {
        const int c = t + j * 256;
        const float v = wr[c] + msk * pt[c];
        x[j] = v; s += v; s2 += v * v;
    }
    #pragma unroll
    for (int o = 32; o > 0; o >>= 1) { s += __shfl_down(s, o); s2 += __shfl_down(s2, o); }
    __shared__ float ls[4], ls2[4];
    if (lane == 0) { ls[wid] = s; ls2[wid] = s2; }
    __syncthreads();
    s  = ls[0] + ls[1] + ls[2] + ls[3];
    s2 = ls2[0] + ls2[1] + ls2[2] + ls2[3];
    const float mean = s * (1.f / 768.f);
    float var = s2 * (1.f / 768.f) - mean * mean;
    var = var < 0.f ? 0.f : var;
    const float inv = 1.f / sqrtf(var + 1e-12f);
    bf16* orow = out + (size_t)row * 768;
    #pragma unroll
    for (int j = 0; j < 3; ++j) {
        const int c = t + j * 256;
        orow[c] = __float2bfloat16((x[j] - mean) * inv * g[c] + b[c]);
    }
}

// ------------- in-place fp32 LN2 over d_out ----------------------------------
__global__ __launch_bounds__(256)
void ln_inplace(float* __restrict__ y, const float* __restrict__ g, const float* __restrict__ b)
{
    const int row = blockIdx.x;
    const int t = threadIdx.x;
    const int lane = t & 63, wid = t >> 6;
    float* yr = y + (size_t)row * 768;
    float x[3];
    float s = 0.f, s2 = 0.f;
    #pragma unroll
    for (int j = 0; j < 3; ++j) {
        const int c = t + j * 256;
        const float v = yr[c];
        x[j] = v; s += v; s2 += v * v;
    }
    #pragma unroll
    for (int o = 32; o > 0; o >>= 1) { s += __shfl_down(s, o); s2 += __shfl_down(s2, o); }
    __shared__ float ls[4], ls2[4];
    if (lane == 0) { ls[wid] = s; ls2[wid] = s2; }
    __syncthreads();
    s  = ls[0] + ls[1] + ls[2] + ls[3];
    s2 = ls2[0] + ls2[1] + ls2[2] + ls2[3];
    const float mean = s * (1.f / 768.f);
    float var = s2 * (1.f / 768.f) - mean * mean;
    var = var < 0.f ? 0.f : var;
    const float inv = 1.f / sqrtf(var + 1e-12f);
    #pragma unroll
    for (int j = 0; j < 3; ++j) {
        const int c = t + j * 256;
        yr[c] = (x[j] - mean) * inv * g[c] + b[c];
    }
}

// ------------- 128x128 MFMA GEMM (m97 structure) -----------------------------
// C[M][N] = A[M][K] @ Bt[N][K]^T, fp32 accum, bf16 operands, fp32 bias.
// EPI 0: C = OutT(relu(acc + bias[n]))            (OutT = bf16)
// EPI 1: C = OutT(acc + bias[n] + resid[m][n])    (OutT = float, resid bf16)
template<int EPI, typename OutT>
__global__ __launch_bounds__(256)
void gemm128(const bf16* __restrict__ A, const bf16* __restrict__ Bt,
             const float* __restrict__ bias, const bf16* __restrict__ resid,
             OutT* __restrict__ C, int N, int K)
{
    __shared__ bf16 As[128 * 32];   // [row][k], 64B rows, unpadded (global_load_lds)
    __shared__ bf16 Bs[128 * 32];   // [col][k]
    const int t = threadIdx.x;
    const int lane = t & 63;
    const int wid  = t >> 6;
    const int quad = lane >> 4;
    const int lr   = lane & 15;
    const int rowBase = blockIdx.y * 128;
    const int colBase = blockIdx.x * 128;   // N in x: A row-block shared in L2
    const int wm = (wid >> 1) * 64;
    const int wn = (wid & 1) * 64;

    f32x4 acc[4][4] = {};

    const char* Ab = (const char*)(A + (size_t)rowBase * K);
    const char* Bb = (const char*)(Bt + (size_t)colBase * K);
    const int strideBytes = K * 2;
    const int i0 = t, i1 = t + 256;
    const int ra0 = i0 >> 2, ca0 = (i0 & 3) * 16;
    const int ra1 = i1 >> 2, ca1 = (i1 & 3) * 16;
    char* AsB = (char*)As;
    char* BsB = (char*)Bs;

    for (int kt = 0; kt < K; kt += 32) {
        const int kb = kt * 2;
        gload_lds16(Ab + (size_t)ra0 * strideBytes + kb + ca0, AsB + i0 * 16);
        gload_lds16(Bb + (size_t)ra0 * strideBytes + kb + ca0, BsB + i0 * 16);
        gload_lds16(Ab + (size_t)ra1 * strideBytes + kb + ca1, AsB + i1 * 16);
        gload_lds16(Bb + (size_t)ra1 * strideBytes + kb + ca1, BsB + i1 * 16);
        __syncthreads();
        short8 af[4], bfr[4];
        #pragma unroll
        for (int mi = 0; mi < 4; ++mi)
            af[mi] = *(const short8*)(AsB + ((wm + mi * 16 + lr) * 64 + quad * 16));
        #pragma unroll
        for (int ni = 0; ni < 4; ++ni)
            bfr[ni] = *(const short8*)(BsB + ((wn + ni * 16 + lr) * 64 + quad * 16));
        #pragma unroll
        for (int mi = 0; mi < 4; ++mi) {
            #pragma unroll
            for (int ni = 0; ni < 4; ++ni)
                acc[mi][ni] = __builtin_amdgcn_mfma_f32_16x16x32_bf16(
                    af[mi], bfr[ni], acc[mi][ni], 0, 0, 0);
        }
        __syncthreads();
    }

    // D layout: row = quad*4 + reg, col = lane&15  [measured m89]
    #pragma unroll
    for (int ni = 0; ni < 4; ++ni) {
        const int gc = colBase + wn + ni * 16 + lr;
        const float bvv = bias[gc];
        #pragma unroll
        for (int mi = 0; mi < 4; ++mi) {
            const int gr0 = rowBase + wm + mi * 16 + quad * 4;
            #pragma unroll
            for (int r = 0; r < 4; ++r) {
                const size_t off = (size_t)(gr0 + r) * N + gc;
                float v = acc[mi][ni][r] + bvv;
                if (EPI == 0) {
                    v = v > 0.f ? v : 0.f;
                    C[off] = (OutT)__float2bfloat16(v);
                } else {
                    v += (float)resid[off];
                    C[off] = (OutT)v;
                }
            }
        }
    }
}

extern "C" void kernel_launch(void* const* d_in, const int* in_sizes, int n_in,
                              void* d_out, int out_size, void* d_ws, size_t ws_size,
                              hipStream_t stream)
{
    const float* we      = (const float*)d_in[0];
    const int*   tags    = (const int*)d_in[1];
    const int*   mask    = (const int*)d_in[2];
    const float* tag_emb = (const float*)d_in[3];
    const float* Wv      = (const float*)d_in[4];
    const float* bv      = (const float*)d_in[5];
    const float* Wo      = (const float*)d_in[6];
    const float* bo      = (const float*)d_in[7];
    const float* ln1g    = (const float*)d_in[8];
    const float* ln1b    = (const float*)d_in[9];
    const float* W1      = (const float*)d_in[10];
    const float* b1      = (const float*)d_in[11];
    const float* W2      = (const float*)d_in[12];
    const float* b2      = (const float*)d_in[13];
    const float* ln2g    = (const float*)d_in[14];
    const float* ln2b    = (const float*)d_in[15];
    float* out = (float*)d_out;

    const int M = 8 * 4096;        // 32768 rows
    const int MC = M / 2;          // 16384-row chunks (halves the hh buffer)
    char* ws = (char*)d_ws;
    float* t1   = (float*)(ws);                 // 64*768*4      = 196608
    float* ptab = (float*)(ws + 196608);        // 64*768*4      = 196608
    bf16*  W1t  = (bf16*)(ws + 393216);         // 3072*768*2    = 4718592
    bf16*  W2t  = (bf16*)(ws + 5111808);        // 768*3072*2    = 4718592
    bf16*  xn   = (bf16*)(ws + 9830400);        // 32768*768*2   = 50331648
    bf16*  hh   = (bf16*)(ws + 60162048);       // 16384*3072*2  = 100663296 (end ~153.6MB)

    // weight transposes+convert: W1t[n][k] = bf16(W1[k][n]); W2t likewise
    transpose_cvt<<<dim3(3072 / 32, 768 / 32), 256, 0, stream>>>(W1, W1t, 768, 3072);
    transpose_cvt<<<dim3(768 / 32, 3072 / 32), 256, 0, stream>>>(W2, W2t, 3072, 768);

    // per-tag table (fp32)
    tag_gemm_a<<<192, 256, 0, stream>>>(tag_emb, Wv, bv, t1);
    tag_gemm_b<<<192, 256, 0, stream>>>(t1, Wo, bo, ptab);

    // xn = bf16(LN1(we + ptab[tag]*mask))
    addtag_ln<<<M, 256, 0, stream>>>(we, tags, mask, ptab, ln1g, ln1b, xn);

    for (int c = 0; c < 2; ++c) {
        const bf16* xnC = xn + (size_t)c * MC * 768;
        // hh = relu(xnC @ W1 + b1)   [bf16]
        gemm128<0, bf16><<<dim3(3072 / 128, MC / 128), 256, 0, stream>>>(
            xnC, W1t, b1, nullptr, hh, 3072, 768);
        // y = hh @ W2 + b2 + xnC  -> d_out chunk (fp32)
        gemm128<1, float><<<dim3(768 / 128, MC / 128), 256, 0, stream>>>(
            hh, W2t, b2, xnC, out + (size_t)c * MC * 768, 768, 3072);
    }

    // out = LN2(y), in place (fp32)
    ln_inplace<<<M, 256, 0, stream>>>(out, ln2g, ln2b);
}

// Round 3
// 820.966 us; speedup vs baseline: 1.1144x; 1.1144x over previous
//
#include <hip/hip_runtime.h>
#include <hip/hip_bf16.h>
#include <cstdint>
#include <cstddef>

typedef __hip_bfloat16 bf16;
typedef __attribute__((ext_vector_type(8))) short short8;
typedef __attribute__((ext_vector_type(4))) float f32x4;

// async global->LDS, 16B per lane. LDS dest = wave-uniform base + lane*16.
__device__ __forceinline__ void gload_lds16(const void* g, void* l) {
    __builtin_amdgcn_global_load_lds((const __attribute__((address_space(1))) void*)g,
                                     (__attribute__((address_space(3))) void*)l,
                                     16, 0, 0);
}

// ------------- fp32 -> bf16 transpose: out[c][r] = bf16(in[r][c]) ------------
__global__ __launch_bounds__(256)
void transpose_cvt(const float* __restrict__ in, bf16* __restrict__ out, int R, int C)
{
    __shared__ float tile[32][33];
    const int tx = threadIdx.x & 31;
    const int ty = threadIdx.x >> 5;      // 0..7
    const int c0 = blockIdx.x * 32;
    const int r0 = blockIdx.y * 32;
    #pragma unroll
    for (int j = 0; j < 32; j += 8)
        tile[ty + j][tx] = in[(size_t)(r0 + ty + j) * C + c0 + tx];
    __syncthreads();
    #pragma unroll
    for (int j = 0; j < 32; j += 8)
        out[(size_t)(c0 + ty + j) * R + r0 + tx] = __float2bfloat16(tile[tx][ty + j]);
}

// ------------- tiny per-tag table gemms (64x768, fp32 all the way) -----------
__global__ __launch_bounds__(256)
void tag_gemm_a(const float* __restrict__ te, const float* __restrict__ Wv,
                const float* __restrict__ bv, float* __restrict__ t1)
{
    const int idx = blockIdx.x * 256 + threadIdx.x;   // 64*768 threads
    const int i = idx / 768, j = idx - i * 768;
    float acc = bv[j];
    const float* a = te + (size_t)i * 768;
    for (int k = 0; k < 768; ++k)
        acc += a[k] * Wv[(size_t)k * 768 + j];
    t1[idx] = acc;
}

__global__ __launch_bounds__(256)
void tag_gemm_b(const float* __restrict__ t1, const float* __restrict__ Wo,
                const float* __restrict__ bo, float* __restrict__ ptab)
{
    const int idx = blockIdx.x * 256 + threadIdx.x;
    const int i = idx / 768, j = idx - i * 768;
    float acc = bo[j];
    const float* a = t1 + (size_t)i * 768;
    for (int k = 0; k < 768; ++k)
        acc += a[k] * Wo[(size_t)k * 768 + j];
    ptab[idx] = acc;
}

// ------------- x = we + ptab[tag]*mask; xn = bf16(LN1(x)) --------------------
__global__ __launch_bounds__(256)
void addtag_ln(const float* __restrict__ we, const int* __restrict__ tags,
               const int* __restrict__ mask, const float* __restrict__ ptab,
               const float* __restrict__ g, const float* __restrict__ b,
               bf16* __restrict__ out)
{
    const int row = blockIdx.x;
    const int t = threadIdx.x;
    const int lane = t & 63, wid = t >> 6;
    const int tag = tags[row];
    const float msk = (float)mask[row];
    const float* wr = we + (size_t)row * 768;
    const float* pt = ptab + (size_t)tag * 768;
    float x[3];
    float s = 0.f, s2 = 0.f;
    #pragma unroll
    for (int j = 0; j < 3; ++j) {
        const int c = t + j * 256;
        const float v = wr[c] + msk * pt[c];
        x[j] = v; s += v; s2 += v * v;
    }
    #pragma unroll
    for (int o = 32; o > 0; o >>= 1) { s += __shfl_down(s, o); s2 += __shfl_down(s2, o); }
    __shared__ float ls[4], ls2[4];
    if (lane == 0) { ls[wid] = s; ls2[wid] = s2; }
    __syncthreads();
    s  = ls[0] + ls[1] + ls[2] + ls[3];
    s2 = ls2[0] + ls2[1] + ls2[2] + ls2[3];
    const float mean = s * (1.f / 768.f);
    float var = s2 * (1.f / 768.f) - mean * mean;
    var = var < 0.f ? 0.f : var;
    const float inv = 1.f / sqrtf(var + 1e-12f);
    bf16* orow = out + (size_t)row * 768;
    #pragma unroll
    for (int j = 0; j < 3; ++j) {
        const int c = t + j * 256;
        orow[c] = __float2bfloat16((x[j] - mean) * inv * g[c] + b[c]);
    }
}

// ------------- in-place fp32 LN2 over d_out ----------------------------------
__global__ __launch_bounds__(256)
void ln_inplace(float* __restrict__ y, const float* __restrict__ g, const float* __restrict__ b)
{
    const int row = blockIdx.x;
    const int t = threadIdx.x;
    const int lane = t & 63, wid = t >> 6;
    float* yr = y + (size_t)row * 768;
    float x[3];
    float s = 0.f, s2 = 0.f;
    #pragma unroll
    for (int j = 0; j < 3; ++j) {
        const int c = t + j * 256;
        const float v = yr[c];
        x[j] = v; s += v; s2 += v * v;
    }
    #pragma unroll
    for (int o = 32; o > 0; o >>= 1) { s += __shfl_down(s, o); s2 += __shfl_down(s2, o); }
    __shared__ float ls[4], ls2[4];
    if (lane == 0) { ls[wid] = s; ls2[wid] = s2; }
    __syncthreads();
    s  = ls[0] + ls[1] + ls[2] + ls[3];
    s2 = ls2[0] + ls2[1] + ls2[2] + ls2[3];
    const float mean = s * (1.f / 768.f);
    float var = s2 * (1.f / 768.f) - mean * mean;
    var = var < 0.f ? 0.f : var;
    const float inv = 1.f / sqrtf(var + 1e-12f);
    #pragma unroll
    for (int j = 0; j < 3; ++j) {
        const int c = t + j * 256;
        yr[c] = (x[j] - mean) * inv * g[c] + b[c];
    }
}

// ------------- 128x128 MFMA GEMM, BK=64, XOR-swizzled LDS --------------------
// C[M][N] = A[M][K] @ Bt[N][K]^T, fp32 accum, bf16 operands, fp32 bias.
// LDS: 128-B rows (64 bf16 of K). Chunk x within a row stores data chunk
// C = x ^ (row&7)  (16-B chunks). Staged via global_load_lds (dest = i*16).
// EPI 0: C = bf16(relu(acc + bias[n]))
// EPI 1: C = fp32(acc + bias[n] + resid[m][n]), resid bf16
template<int EPI, typename OutT>
__global__ __launch_bounds__(256)
void gemm128(const bf16* __restrict__ A, const bf16* __restrict__ Bt,
             const float* __restrict__ bias, const bf16* __restrict__ resid,
             OutT* __restrict__ C, int N, int K)
{
    __shared__ bf16 As[128 * 64];   // 16 KB
    __shared__ bf16 Bs[128 * 64];   // 16 KB
    const int t = threadIdx.x;
    const int lane = t & 63;
    const int wid  = t >> 6;
    const int quad = lane >> 4;
    const int lr   = lane & 15;
    const int rowBase = blockIdx.y * 128;
    const int colBase = blockIdx.x * 128;   // N in x: A row-block shared in L2
    const int wm = (wid >> 1) * 64;
    const int wn = (wid & 1) * 64;

    f32x4 acc[4][4] = {};

    const char* Ab = (const char*)(A + (size_t)rowBase * K);
    const char* Bb = (const char*)(Bt + (size_t)colBase * K);
    const int strideBytes = K * 2;
    char* AsB = (char*)As;
    char* BsB = (char*)Bs;

    // precompute staging (row, swizzled-chunk) for the 4 issues per thread
    int srow[4], soff[4];
    #pragma unroll
    for (int p = 0; p < 4; ++p) {
        const int i = t + p * 256;
        srow[p] = i >> 3;                         // 0..127
        soff[p] = ((i & 7) ^ (srow[p] & 7)) * 16; // swizzled byte chunk in row
    }

    for (int kt = 0; kt < K; kt += 64) {
        const int kb = kt * 2;
        #pragma unroll
        for (int p = 0; p < 4; ++p) {
            const int i = t + p * 256;
            gload_lds16(Ab + (size_t)srow[p] * strideBytes + kb + soff[p], AsB + i * 16);
            gload_lds16(Bb + (size_t)srow[p] * strideBytes + kb + soff[p], BsB + i * 16);
        }
        __syncthreads();
        #pragma unroll
        for (int j = 0; j < 2; ++j) {             // two K=32 slices of the 64-tile
            const int cch = j * 4 + quad;         // 16-B data-chunk index 0..7
            short8 af[4], bfr[4];
            #pragma unroll
            for (int mi = 0; mi < 4; ++mi) {
                const int R = wm + mi * 16 + lr;
                af[mi] = *(const short8*)(AsB + R * 128 + ((cch ^ (R & 7)) * 16));
            }
            #pragma unroll
            for (int ni = 0; ni < 4; ++ni) {
                const int R = wn + ni * 16 + lr;
                bfr[ni] = *(const short8*)(BsB + R * 128 + ((cch ^ (R & 7)) * 16));
            }
            #pragma unroll
            for (int mi = 0; mi < 4; ++mi) {
                #pragma unroll
                for (int ni = 0; ni < 4; ++ni)
                    acc[mi][ni] = __builtin_amdgcn_mfma_f32_16x16x32_bf16(
                        af[mi], bfr[ni], acc[mi][ni], 0, 0, 0);
            }
        }
        __syncthreads();
    }

    // D layout: row = quad*4 + reg, col = lane&15  [measured m89]
    #pragma unroll
    for (int ni = 0; ni < 4; ++ni) {
        const int gc = colBase + wn + ni * 16 + lr;
        const float bvv = bias[gc];
        #pragma unroll
        for (int mi = 0; mi < 4; ++mi) {
            const int gr0 = rowBase + wm + mi * 16 + quad * 4;
            #pragma unroll
            for (int r = 0; r < 4; ++r) {
                const size_t off = (size_t)(gr0 + r) * N + gc;
                float v = acc[mi][ni][r] + bvv;
                if (EPI == 0) {
                    v = v > 0.f ? v : 0.f;
                    C[off] = (OutT)__float2bfloat16(v);
                } else {
                    v += (float)resid[off];
                    C[off] = (OutT)v;
                }
            }
        }
    }
}

extern "C" void kernel_launch(void* const* d_in, const int* in_sizes, int n_in,
                              void* d_out, int out_size, void* d_ws, size_t ws_size,
                              hipStream_t stream)
{
    const float* we      = (const float*)d_in[0];
    const int*   tags    = (const int*)d_in[1];
    const int*   mask    = (const int*)d_in[2];
    const float* tag_emb = (const float*)d_in[3];
    const float* Wv      = (const float*)d_in[4];
    const float* bv      = (const float*)d_in[5];
    const float* Wo      = (const float*)d_in[6];
    const float* bo      = (const float*)d_in[7];
    const float* ln1g    = (const float*)d_in[8];
    const float* ln1b    = (const float*)d_in[9];
    const float* W1      = (const float*)d_in[10];
    const float* b1      = (const float*)d_in[11];
    const float* W2      = (const float*)d_in[12];
    const float* b2      = (const float*)d_in[13];
    const float* ln2g    = (const float*)d_in[14];
    const float* ln2b    = (const float*)d_in[15];
    float* out = (float*)d_out;

    const int M = 8 * 4096;        // 32768 rows
    char* ws = (char*)d_ws;
    const size_t oT1   = 0;                    // 64*768*4      = 196608
    const size_t oPtab = 196608;               // 64*768*4      = 196608
    const size_t oW1t  = 393216;               // 3072*768*2    = 4718592
    const size_t oW2t  = 5111808;              // 768*3072*2    = 4718592
    const size_t oXn   = 9830400;              // 32768*768*2   = 50331648
    const size_t oHh   = 60162048;
    const size_t hhFull = (size_t)M * 3072 * 2;        // 201326592

    // single pass over M if workspace allows (bigger grids = more latency hiding)
    const int nchunk = (ws_size >= oHh + hhFull) ? 1 : 2;
    const int MC = M / nchunk;

    float* t1   = (float*)(ws + oT1);
    float* ptab = (float*)(ws + oPtab);
    bf16*  W1t  = (bf16*)(ws + oW1t);
    bf16*  W2t  = (bf16*)(ws + oW2t);
    bf16*  xn   = (bf16*)(ws + oXn);
    bf16*  hh   = (bf16*)(ws + oHh);           // MC*3072*2

    // weight transposes+convert: W1t[n][k] = bf16(W1[k][n]); W2t likewise
    transpose_cvt<<<dim3(3072 / 32, 768 / 32), 256, 0, stream>>>(W1, W1t, 768, 3072);
    transpose_cvt<<<dim3(768 / 32, 3072 / 32), 256, 0, stream>>>(W2, W2t, 3072, 768);

    // per-tag table (fp32)
    tag_gemm_a<<<192, 256, 0, stream>>>(tag_emb, Wv, bv, t1);
    tag_gemm_b<<<192, 256, 0, stream>>>(t1, Wo, bo, ptab);

    // xn = bf16(LN1(we + ptab[tag]*mask))
    addtag_ln<<<M, 256, 0, stream>>>(we, tags, mask, ptab, ln1g, ln1b, xn);

    for (int c = 0; c < nchunk; ++c) {
        const bf16* xnC = xn + (size_t)c * MC * 768;
        // hh = relu(xnC @ W1 + b1)   [bf16]
        gemm128<0, bf16><<<dim3(3072 / 128, MC / 128), 256, 0, stream>>>(
            xnC, W1t, b1, nullptr, hh, 3072, 768);
        // y = hh @ W2 + b2 + xnC  -> d_out chunk (fp32)
        gemm128<1, float><<<dim3(768 / 128, MC / 128), 256, 0, stream>>>(
            hh, W2t, b2, xnC, out + (size_t)c * MC * 768, 768, 3072);
    }

    // out = LN2(y), in place (fp32)
    ln_inplace<<<M, 256, 0, stream>>>(out, ln2g, ln2b);
}